// Round 8
// baseline (648.450 us; speedup 1.0000x reference)
//
#include <hip/hip_runtime.h>
#include <stdint.h>

// MemoryDiscriminator: embed-GEMM + LeakyReLU + BN(fold into GEMM2) + dual GRU scan + cosine gate.
// Key identities: hm is batch-uniform; only t=T-1 output needed; gi_x hoisted out of scan.
// R8: fusion abandoned (R5-R7: per-step agent-acquire flag polling = vmcnt drain + cache inv +
//     cross-XCD latency every step -> consumer 2x slower than flag-free R3). Clean pipeline:
//     gemm_gi (standalone, 128x384 tiles) writes PERMUTED gperm (48 contiguous B per lane-step);
//     recurrence prefetches gates into named VGPR scalars depth-2 (no flags -> no ordering needed)
//     and uses an lgkm-only barrier so prefetch loads stay in flight across steps.

typedef float  f32x4 __attribute__((ext_vector_type(4)));
typedef __bf16 bf16x8 __attribute__((ext_vector_type(8)));
typedef unsigned short u16;

// ---------------- workspace layout (bytes) ----------------
static constexpr size_t OFF_XB    = 0;          // 32768*128 bf16   = 8,388,608
static constexpr size_t OFF_WEMB  = 8388608;    // 1024*128 bf16    = 262,144
static constexpr size_t OFF_WHX   = 8650752;    // 768*256 bf16     = 393,216
static constexpr size_t OFF_WHM   = 9043968;    // 768*256 bf16     = 393,216
static constexpr size_t OFF_SUM   = 9437184;    // 1024 f32
static constexpr size_t OFF_SSQ   = 9441280;    // 1024 f32
static constexpr size_t OFF_BIASX = 9453568;    // 768 f32 (padded)
static constexpr size_t OFF_GIM   = 9457664;    // 128*768 bf16     = 196,608
static constexpr size_t OFF_EACT  = 9654272;    // 32768*1024 bf16  = 67,108,864
static constexpr size_t OFF_GI    = 76763136;   // gperm: 128t*16wg*8v*64lane*24 u16 = 50,331,648
static constexpr size_t OFF_HXF   = 127094784;  // 256*256 f32
static constexpr size_t OFF_HMF   = 127356928;  // 16*256 f32
static constexpr size_t OFF_WPX   = 127373312;  // 768*1024 bf16    = 1,572,864
// total ~128.9 MB

__device__ __forceinline__ float sigmoidf_(float x) {
    return __builtin_amdgcn_rcpf(1.0f + __expf(-x));
}
__device__ __forceinline__ float tanhf_(float x) {
    return 1.0f - 2.0f * __builtin_amdgcn_rcpf(1.0f + __expf(2.0f * x));
}
__device__ __forceinline__ float bf16bits_(u16 u) {
    return __uint_as_float(((unsigned)u) << 16);
}
__device__ __forceinline__ u16 f2bf_(float f) {
    __bf16 h = (__bf16)f;
    return __builtin_bit_cast(u16, h);
}
__device__ __forceinline__ void gload_lds16(const void* g, void* l) {
    __builtin_amdgcn_global_load_lds(
        (const __attribute__((address_space(1))) unsigned int*)g,
        (__attribute__((address_space(3))) unsigned int*)l, 16, 0, 0);
}
// barrier that orders LDS only -- leaves global loads (vmcnt) in flight across it
__device__ __forceinline__ void barrier_nodrain() {
    __asm__ volatile("s_waitcnt lgkmcnt(0)\n\ts_barrier" ::: "memory");
}

// ---------------- K0: fp32->bf16 conversions + zero stats ----------------
__global__ void prep(const float* __restrict__ x, const float* __restrict__ wemb,
                     const float* __restrict__ whx, const float* __restrict__ whm,
                     __bf16* __restrict__ xb, __bf16* __restrict__ wembb,
                     __bf16* __restrict__ whxb, __bf16* __restrict__ whmb,
                     float* __restrict__ stats /*2048*/)
{
    long i = (long)blockIdx.x * 256 + threadIdx.x;
    if (i < 2048) stats[i] = 0.0f;
    if (i < 4194304)      xb[i] = (__bf16)x[i];
    else if (i < 4325376) wembb[i - 4194304] = (__bf16)wemb[i - 4194304];
    else if (i < 4521984) whxb[i - 4325376]  = (__bf16)whx[i - 4325376];
    else if (i < 4718592) whmb[i - 4521984]  = (__bf16)whm[i - 4521984];
}

// ---------------- K1: eact GEMM (+bias, LeakyReLU, BN stats), 128x128 tile, BK=32 ----------------
__launch_bounds__(256)
__global__ void gemm_e(const __bf16* __restrict__ A, const __bf16* __restrict__ Bm,
                       const float* __restrict__ bias, __bf16* __restrict__ C,
                       float* __restrict__ sums, float* __restrict__ ssqs,
                       int K, int N)
{
    __shared__ __bf16 As[128 * 32];
    __shared__ __bf16 Bs[128 * 32];
    const int tid  = threadIdx.x;
    const int lane = tid & 63;
    const int wv   = tid >> 6;
    const int wm   = wv >> 1, wn = wv & 1;
    const int l15  = lane & 15, quad = lane >> 4;
    const long m0 = (long)blockIdx.x * 128;
    const long n0 = (long)blockIdx.y * 128;

    const int srow = lane >> 2;
    const int scol = (lane & 3) * 8;
    const __bf16* ag[2]; const __bf16* bg[2];
    __bf16* al[2]; __bf16* bl[2];
#pragma unroll
    for (int j = 0; j < 2; j++) {
        const int s = wv * 2 + j;
        ag[j] = A  + (m0 + s * 16 + srow) * K + scol;
        bg[j] = Bm + (n0 + s * 16 + srow) * K + scol;
        al[j] = &As[s * 512];
        bl[j] = &Bs[s * 512];
    }

    const f32x4 fz = {0.f, 0.f, 0.f, 0.f};
    f32x4 acc[4][4];
#pragma unroll
    for (int i = 0; i < 4; i++)
#pragma unroll
        for (int j = 0; j < 4; j++) acc[i][j] = fz;

    for (int k0 = 0; k0 < K; k0 += 32) {
        __syncthreads();
        gload_lds16(ag[0] + k0, al[0]);
        gload_lds16(ag[1] + k0, al[1]);
        gload_lds16(bg[0] + k0, bl[0]);
        gload_lds16(bg[1] + k0, bl[1]);
        __syncthreads();
        bf16x8 af[4], bfr[4];
#pragma unroll
        for (int mt = 0; mt < 4; mt++)
            af[mt] = *(const bf16x8*)(&As[(wm * 64 + mt * 16 + l15) * 32 + quad * 8]);
#pragma unroll
        for (int nt = 0; nt < 4; nt++)
            bfr[nt] = *(const bf16x8*)(&Bs[(wn * 64 + nt * 16 + l15) * 32 + quad * 8]);
#pragma unroll
        for (int mt = 0; mt < 4; mt++)
#pragma unroll
            for (int nt = 0; nt < 4; nt++)
                acc[mt][nt] = __builtin_amdgcn_mfma_f32_16x16x32_bf16(af[mt], bfr[nt], acc[mt][nt], 0, 0, 0);
    }

#pragma unroll
    for (int nt = 0; nt < 4; nt++) {
        const long ncol = n0 + wn * 64 + nt * 16 + l15;
        const float bi = bias[ncol];
        float s = 0.f, ss = 0.f;
#pragma unroll
        for (int mt = 0; mt < 4; mt++) {
#pragma unroll
            for (int r = 0; r < 4; r++) {
                float v = acc[mt][nt][r] + bi;
                v = (v >= 0.f) ? v : 0.2f * v;
                __bf16 hv = (__bf16)v;
                C[(m0 + wm * 64 + mt * 16 + quad * 4 + r) * (long)N + ncol] = hv;
                float fv = (float)hv; s += fv; ss += fv * fv;
            }
        }
        s += __shfl_xor(s, 16);  ss += __shfl_xor(ss, 16);
        s += __shfl_xor(s, 32);  ss += __shfl_xor(ss, 32);
        if (lane < 16) {
            atomicAdd(&sums[n0 + wn * 64 + nt * 16 + lane], s);
            atomicAdd(&ssqs[n0 + wn * 64 + nt * 16 + lane], ss);
        }
    }
}

// ---------------- K2: build_wp (blocks 0..767) + build_gim (blocks 768..3839) merged ----------------
__global__ void build_misc(const float* __restrict__ w_ih_x, const float* __restrict__ b_ih_x,
                           const float* __restrict__ b_hh_x, const float* __restrict__ sums,
                           const float* __restrict__ ssqs, const float* __restrict__ gamma,
                           const float* __restrict__ beta, __bf16* __restrict__ wpx,
                           float* __restrict__ biasx,
                           const float* __restrict__ memory, const float* __restrict__ w_ih_m,
                           const float* __restrict__ b_ih_m, const float* __restrict__ b_hh_m,
                           __bf16* __restrict__ gim)
{
    const int lane = threadIdx.x;  // 64
    if (blockIdx.x < 768) {
        const int j = blockIdx.x;
        const float inv = 1.0f / 32768.0f;
        float accv = 0.f;
#pragma unroll
        for (int i = 0; i < 16; i++) {
            int h = i * 64 + lane;
            float mean = sums[h] * inv;
            float var  = ssqs[h] * inv - mean * mean;
            float s    = rsqrtf(var + 1e-5f) * gamma[h];
            float c    = beta[h] - mean * s;
            float w = w_ih_x[(long)j * 1024 + h];
            wpx[(long)j * 1024 + h] = (__bf16)(w * s);
            accv += c * w;
        }
        for (int off = 32; off; off >>= 1) accv += __shfl_xor(accv, off);
        if (lane == 0) biasx[j] = accv + b_ih_x[j] + (j < 512 ? b_hh_x[j] : 0.0f);
    } else {
        const int g  = blockIdx.x - 768;
        const int jj = g % 768;
        const int t0 = (g / 768) * 32;
        float w[16];
#pragma unroll
        for (int i = 0; i < 16; i++) w[i] = w_ih_m[(long)jj * 1024 + i * 64 + lane];
        const float bb = b_ih_m[jj] + (jj < 512 ? b_hh_m[jj] : 0.0f);
        for (int t = t0; t < t0 + 32; t++) {
            float s = 0.f;
#pragma unroll
            for (int i = 0; i < 16; i++) s += w[i] * memory[(long)t * 1024 + i * 64 + lane];
            for (int off = 32; off; off >>= 1) s += __shfl_xor(s, off);
            if (lane == 0) gim[t * 768 + jj] = (__bf16)(s + bb);
        }
    }
}

// ---------------- K3: gi GEMM producing PERMUTED gperm, 128x384 tile ----------------
// blockIdx g: mt = g>>1 (t = mt>>1, bhalf = mt&1), nh = g&1 (384-col half).
// gperm u16 index = ((t*16 + wg)*8 + v)*1536 + lane*24 + gate*8 + r*2 + ct
__launch_bounds__(512, 2)
__global__ void gemm_gi(const __bf16* __restrict__ eact, const __bf16* __restrict__ wpx,
                        const float* __restrict__ biasx, __bf16* __restrict__ gperm)
{
    __shared__ __bf16 As[128 * 32];
    __shared__ __bf16 Bs[384 * 32];
    const int tid  = threadIdx.x;
    const int lane = tid & 63;
    const int v    = tid >> 6;
    const int l15  = lane & 15, quad = lane >> 4;

    const int g   = blockIdx.x;        // 0..511
    const int mt  = g >> 1;
    const int nh  = g & 1;
    const int t   = mt >> 1, bhalf = mt & 1;
    const int c0  = nh * 384;
    const int mh  = v >> 2, q = v & 3; // wave: rows mh*64+.., cols q*96+..
    const int srow = lane >> 2, scol = (lane & 3) * 8;

    const __bf16* agA = eact + ((long)(bhalf * 128 + v * 16 + srow) * 128 + t) * 1024 + scol;
    __bf16* alA = &As[v * 512];
    const __bf16* agB[3]; __bf16* blB[3];
#pragma unroll
    for (int sub = 0; sub < 3; sub++) {
        agB[sub] = wpx + (long)(c0 + v * 48 + sub * 16 + srow) * 1024 + scol;
        blB[sub] = &Bs[(v * 3 + sub) * 512];
    }

    const f32x4 fz = {0.f, 0.f, 0.f, 0.f};
    f32x4 acc[4][6];
#pragma unroll
    for (int i = 0; i < 4; i++)
#pragma unroll
        for (int j = 0; j < 6; j++) acc[i][j] = fz;

    for (int k0 = 0; k0 < 1024; k0 += 32) {
        __syncthreads();
        gload_lds16(agA + k0, alA);
        gload_lds16(agB[0] + k0, blB[0]);
        gload_lds16(agB[1] + k0, blB[1]);
        gload_lds16(agB[2] + k0, blB[2]);
        __syncthreads();
        bf16x8 af[4], bfr[6];
#pragma unroll
        for (int i = 0; i < 4; i++)
            af[i] = *(const bf16x8*)(&As[(mh * 64 + i * 16 + l15) * 32 + quad * 8]);
#pragma unroll
        for (int j = 0; j < 6; j++)
            bfr[j] = *(const bf16x8*)(&Bs[(q * 96 + j * 16 + l15) * 32 + quad * 8]);
#pragma unroll
        for (int i = 0; i < 4; i++)
#pragma unroll
            for (int j = 0; j < 6; j++)
                acc[i][j] = __builtin_amdgcn_mfma_f32_16x16x32_bf16(af[i], bfr[j], acc[i][j], 0, 0, 0);
    }

    float bi[6];
#pragma unroll
    for (int j = 0; j < 6; j++) bi[j] = biasx[c0 + q * 96 + j * 16 + l15];

    u16* gp = (u16*)gperm;
#pragma unroll
    for (int i = 0; i < 4; i++) {
        const int wgi = bhalf * 8 + mh * 4 + i;
#pragma unroll
        for (int jp = 0; jp < 3; jp++) {
            const int cbase = c0 + q * 96 + jp * 32;
            const int gg = cbase >> 8;
            const int vc = (cbase >> 5) & 7;
            unsigned wbits[4];
#pragma unroll
            for (int r = 0; r < 4; r++) {
                u16 lo = f2bf_(acc[i][2 * jp + 0][r] + bi[2 * jp + 0]);
                u16 hi = f2bf_(acc[i][2 * jp + 1][r] + bi[2 * jp + 1]);
                wbits[r] = (unsigned)lo | ((unsigned)hi << 16);
            }
            uint4 o = {wbits[0], wbits[1], wbits[2], wbits[3]};
            const long idx = (((long)t * 16 + wgi) * 8 + vc) * 1536 + (long)lane * 24 + gg * 8;
            *(uint4*)(gp + idx) = o;
        }
    }
}

// ---------------- K4: GRU recurrence. wg 0..15: 16 batch rows; wg 16: hm (batch-uniform). ----------------
// 8 waves. Gate inputs prefetched depth-2 into NAMED register scalars (no address-taken arrays,
// no flags/atomics -> loads need no ordering); lgkm-only barrier keeps them in flight.
__launch_bounds__(512, 2)
__global__ void recurrence(const __bf16* __restrict__ gperm, const __bf16* __restrict__ gim,
                           const __bf16* __restrict__ whx, const __bf16* __restrict__ whm,
                           const float* __restrict__ bhhx, const float* __restrict__ bhhm,
                           float* __restrict__ hxfin, float* __restrict__ hmfin)
{
    __shared__ __bf16 hxl[2][16 * 264];
    const int tid  = threadIdx.x;
    const int lane = tid & 63;
    const int v    = tid >> 6;     // wave 0..7
    const int l15  = lane & 15, quad = lane >> 4;
    const int wg   = blockIdx.x;   // 0..16
    const bool isX = (wg < 16);
    const __bf16* wh  = isX ? whx : whm;
    const float*  bhh = isX ? bhhx : bhhm;

    bf16x8 W[6][8];
#pragma unroll
    for (int nt = 0; nt < 6; nt++) {
        const int gg = nt >> 1, ct = nt & 1;
        const long j = gg * 256 + (v * 2 + ct) * 16 + l15;
#pragma unroll
        for (int kt = 0; kt < 8; kt++)
            W[nt][kt] = *(const bf16x8*)(wh + j * 256 + kt * 32 + quad * 8);
    }
    float bhhn[2];
#pragma unroll
    for (int ct = 0; ct < 2; ct++) bhhn[ct] = bhh[512 + v * 32 + ct * 16 + l15];

    for (int i = tid; i < 16 * 264; i += 512) hxl[0][i] = (__bf16)0.f;

    float st[8];
#pragma unroll
    for (int i = 0; i < 8; i++) st[i] = 0.f;

    const char* gpbase = (const char*)gperm + ((long)wg * 8 + v) * 3072 + (long)lane * 48;
    const u16*  gmb    = (const u16*)gim + (v * 32 + l15);

    uint4 qa0, qa1, qa2, qb0, qb1, qb2;
    u16 ha0 = 0, ha1 = 0, ha2 = 0, ha3 = 0, ha4 = 0, ha5 = 0;
    u16 hb0 = 0, hb1 = 0, hb2 = 0, hb3 = 0, hb4 = 0, hb5 = 0;
    qa0 = qa1 = qa2 = qb0 = qb1 = qb2 = uint4{0, 0, 0, 0};

#define LOADX(T, q0, q1, q2) do { \
        const uint4* _p = (const uint4*)(gpbase + (long)(T) * 393216); \
        q0 = _p[0]; q1 = _p[1]; q2 = _p[2]; } while (0)
#define LOADM(T, h0, h1, h2, h3, h4, h5) do { \
        const u16* _p = gmb + (long)(T) * 768; \
        h0 = _p[0]; h1 = _p[16]; h2 = _p[256]; h3 = _p[272]; h4 = _p[512]; h5 = _p[528]; } while (0)

    if (isX) { LOADX(0, qa0, qa1, qa2); LOADX(1, qb0, qb1, qb2); }
    else     { LOADM(0, ha0, ha1, ha2, ha3, ha4, ha5); LOADM(1, hb0, hb1, hb2, hb3, hb4, hb5); }
    __syncthreads();   // hxl[0] zero-init visible (one-time full drain is fine)

    auto do_step = [&](int cur, uint4 q0, uint4 q1, uint4 q2,
                       u16 h0, u16 h1, u16 h2, u16 h3, u16 h4, u16 h5) {
        const f32x4 fz = {0.f, 0.f, 0.f, 0.f};
        f32x4 acc[6];
#pragma unroll
        for (int nt = 0; nt < 6; nt++) acc[nt] = fz;
        const __bf16* hxc = &hxl[cur][0];
#pragma unroll
        for (int kt = 0; kt < 8; kt++) {
            bf16x8 a = *(const bf16x8*)(hxc + l15 * 264 + kt * 32 + quad * 8);
#pragma unroll
            for (int nt = 0; nt < 6; nt++)
                acc[nt] = __builtin_amdgcn_mfma_f32_16x16x32_bf16(a, W[nt][kt], acc[nt], 0, 0, 0);
        }
        __bf16* hxn = &hxl[cur ^ 1][0];
#pragma unroll
        for (int ct = 0; ct < 2; ct++) {
            const int ob = v * 32 + ct * 16 + l15;
#pragma unroll
            for (int r = 0; r < 4; r++) {
                float gr, gz, gn;
                if (isX) {
                    const unsigned ur = (r == 0) ? q0.x : (r == 1) ? q0.y : (r == 2) ? q0.z : q0.w;
                    const unsigned uz = (r == 0) ? q1.x : (r == 1) ? q1.y : (r == 2) ? q1.z : q1.w;
                    const unsigned un = (r == 0) ? q2.x : (r == 1) ? q2.y : (r == 2) ? q2.z : q2.w;
                    gr = __uint_as_float(ct ? (ur & 0xffff0000u) : (ur << 16));
                    gz = __uint_as_float(ct ? (uz & 0xffff0000u) : (uz << 16));
                    gn = __uint_as_float(ct ? (un & 0xffff0000u) : (un << 16));
                } else {
                    gr = bf16bits_(ct ? h1 : h0);
                    gz = bf16bits_(ct ? h3 : h2);
                    gn = bf16bits_(ct ? h5 : h4);
                }
                const float rg = sigmoidf_(gr + acc[ct][r]);
                const float zg = sigmoidf_(gz + acc[2 + ct][r]);
                const float ng = tanhf_(gn + rg * (acc[4 + ct][r] + bhhn[ct]));
                float h = st[ct * 4 + r];
                h = ng + zg * (h - ng);
                st[ct * 4 + r] = h;
                hxn[(quad * 4 + r) * 264 + ob] = (__bf16)h;
            }
        }
    };

    for (int t = 0; t < 128; t += 2) {
        do_step(0, qa0, qa1, qa2, ha0, ha1, ha2, ha3, ha4, ha5);
        if (t + 2 < 128) {
            if (isX) LOADX(t + 2, qa0, qa1, qa2);
            else     LOADM(t + 2, ha0, ha1, ha2, ha3, ha4, ha5);
        }
        barrier_nodrain();
        do_step(1, qb0, qb1, qb2, hb0, hb1, hb2, hb3, hb4, hb5);
        if (t + 3 < 128) {
            if (isX) LOADX(t + 3, qb0, qb1, qb2);
            else     LOADM(t + 3, hb0, hb1, hb2, hb3, hb4, hb5);
        }
        barrier_nodrain();
    }
#undef LOADX
#undef LOADM

    float* finp = isX ? (hxfin + (long)wg * 16 * 256) : hmfin;
#pragma unroll
    for (int ct = 0; ct < 2; ct++) {
        const int ob = v * 32 + ct * 16 + l15;
#pragma unroll
        for (int r = 0; r < 4; r++)
            finp[(quad * 4 + r) * 256 + ob] = st[ct * 4 + r];
    }
}

// ---------------- K5: cosine gate at t=T-1 -> output ----------------
__global__ void finalize(const float* __restrict__ hxfin, const float* __restrict__ hmfin,
                         const float* __restrict__ W_sx, const float* __restrict__ b_sx,
                         const float* __restrict__ W_sm, const float* __restrict__ b_sm,
                         float* __restrict__ out)
{
    const int b = blockIdx.x;      // 256
    const int lane = threadIdx.x;  // 64
    float qx[4], qm[4];
#pragma unroll
    for (int s = 0; s < 4; s++) {
        float px = 0.f, pm = 0.f;
#pragma unroll
        for (int i = 0; i < 4; i++) {
            int h = i * 64 + lane;
            px += W_sx[s * 256 + h] * hxfin[b * 256 + h];
            pm += W_sm[s * 256 + h] * hmfin[h];
        }
        for (int off = 32; off; off >>= 1) { px += __shfl_xor(px, off); pm += __shfl_xor(pm, off); }
        qx[s] = px + b_sx[s];
        qm[s] = pm + b_sm[s];
    }
    float num = 0.f, nx = 0.f, nm = 0.f;
#pragma unroll
    for (int s = 0; s < 4; s++) { num += qx[s] * qm[s]; nx += qx[s] * qx[s]; nm += qm[s] * qm[s]; }
    const float den = fmaxf(sqrtf(nx), 1e-8f) * fmaxf(sqrtf(nm), 1e-8f);
    const float g = 1.0f / (1.0f + __expf(-num / den));
#pragma unroll
    for (int i = 0; i < 4; i++) {
        int h = i * 64 + lane;
        out[b * 256 + h] = g * hxfin[b * 256 + h] + (1.0f - g) * hmfin[h];
    }
}

extern "C" void kernel_launch(void* const* d_in, const int* in_sizes, int n_in,
                              void* d_out, int out_size, void* d_ws, size_t ws_size,
                              hipStream_t stream)
{
    (void)in_sizes; (void)n_in; (void)out_size; (void)ws_size;
    const float* x      = (const float*)d_in[0];
    const float* W_emb  = (const float*)d_in[1];
    const float* b_emb  = (const float*)d_in[2];
    const float* gamma  = (const float*)d_in[3];
    const float* beta   = (const float*)d_in[4];
    const float* memory = (const float*)d_in[5];
    const float* w_ih_x = (const float*)d_in[6];
    const float* w_hh_x = (const float*)d_in[7];
    const float* b_ih_x = (const float*)d_in[8];
    const float* b_hh_x = (const float*)d_in[9];
    const float* w_ih_m = (const float*)d_in[10];
    const float* w_hh_m = (const float*)d_in[11];
    const float* b_ih_m = (const float*)d_in[12];
    const float* b_hh_m = (const float*)d_in[13];
    const float* W_sx   = (const float*)d_in[14];
    const float* b_sx   = (const float*)d_in[15];
    const float* W_sm   = (const float*)d_in[16];
    const float* b_sm   = (const float*)d_in[17];
    float* out = (float*)d_out;
    char* ws = (char*)d_ws;

    __bf16* xb    = (__bf16*)(ws + OFF_XB);
    __bf16* wembb = (__bf16*)(ws + OFF_WEMB);
    __bf16* whxb  = (__bf16*)(ws + OFF_WHX);
    __bf16* whmb  = (__bf16*)(ws + OFF_WHM);
    float*  sums  = (float*)(ws + OFF_SUM);
    float*  ssqs  = (float*)(ws + OFF_SSQ);
    float*  biasx = (float*)(ws + OFF_BIASX);
    __bf16* gim   = (__bf16*)(ws + OFF_GIM);
    __bf16* eact  = (__bf16*)(ws + OFF_EACT);
    __bf16* gperm = (__bf16*)(ws + OFF_GI);
    float*  hxf   = (float*)(ws + OFF_HXF);
    float*  hmf   = (float*)(ws + OFF_HMF);
    __bf16* wpx   = (__bf16*)(ws + OFF_WPX);

    prep<<<18432, 256, 0, stream>>>(x, W_emb, w_hh_x, w_hh_m, xb, wembb, whxb, whmb, sums);
    gemm_e<<<dim3(256, 8), 256, 0, stream>>>(xb, wembb, b_emb, eact, sums, ssqs, 128, 1024);
    build_misc<<<3840, 64, 0, stream>>>(w_ih_x, b_ih_x, b_hh_x, sums, ssqs, gamma, beta, wpx, biasx,
                                        memory, w_ih_m, b_ih_m, b_hh_m, gim);
    gemm_gi<<<512, 512, 0, stream>>>(eact, wpx, biasx, gperm);
    recurrence<<<17, 512, 0, stream>>>(gperm, gim, whxb, whmb, b_hh_x, b_hh_m, hxf, hmf);
    finalize<<<256, 64, 0, stream>>>(hxf, hmf, W_sx, b_sx, W_sm, b_sm, out);
}

// Round 9
// 640.111 us; speedup vs baseline: 1.0130x; 1.0130x over previous
//
#include <hip/hip_runtime.h>
#include <stdint.h>

// MemoryDiscriminator: embed-GEMM + LeakyReLU + BN(fold into GEMM2) + dual GRU scan + cosine gate.
// Key identities: hm is batch-uniform; only t=T-1 output needed; gi_x hoisted out of scan.
// R9: gperm v2 = per-(wg,wave,gate) LANE-LINEAR 16B/lane regions. Producer stores coalesced;
//     consumer = R3's proven structure (global_load_lds staging + one __syncthreads/step) but
//     gate phase reads 3x ds_read_b128 + shift-unpack (was 24 ds_read_u16 + addr math).
//     MFMA split ct0-pass/ct1-pass so ct0 gate VALU overlaps ct1 MFMA drain.
//     (R8 lesson: 48B-stride VMEM on either producer or consumer side = 3x request
//      amplification -> unhideable latency. Both sides now lane-linear.)

typedef float  f32x4 __attribute__((ext_vector_type(4)));
typedef __bf16 bf16x8 __attribute__((ext_vector_type(8)));
typedef unsigned short u16;

// ---------------- workspace layout (bytes) ----------------
static constexpr size_t OFF_XB    = 0;          // 32768*128 bf16   = 8,388,608
static constexpr size_t OFF_WEMB  = 8388608;    // 1024*128 bf16    = 262,144
static constexpr size_t OFF_WHX   = 8650752;    // 768*256 bf16     = 393,216
static constexpr size_t OFF_WHM   = 9043968;    // 768*256 bf16     = 393,216
static constexpr size_t OFF_SUM   = 9437184;    // 1024 f32
static constexpr size_t OFF_SSQ   = 9441280;    // 1024 f32
static constexpr size_t OFF_BIASX = 9453568;    // 768 f32 (padded)
static constexpr size_t OFF_GIM   = 9457664;    // 128*768 bf16     = 196,608
static constexpr size_t OFF_EACT  = 9654272;    // 32768*1024 bf16  = 67,108,864
static constexpr size_t OFF_GI    = 76763136;   // gperm v2: 128t * 16wg * 8v * 3g * 512 u16 = 50,331,648
static constexpr size_t OFF_HXF   = 127094784;  // 256*256 f32
static constexpr size_t OFF_HMF   = 127356928;  // 16*256 f32
static constexpr size_t OFF_WPX   = 127373312;  // 768*1024 bf16    = 1,572,864
// total ~128.9 MB

__device__ __forceinline__ float sigmoidf_(float x) {
    return __builtin_amdgcn_rcpf(1.0f + __expf(-x));
}
__device__ __forceinline__ float tanhf_(float x) {
    return 1.0f - 2.0f * __builtin_amdgcn_rcpf(1.0f + __expf(2.0f * x));
}
__device__ __forceinline__ float bf16bits_(u16 u) {
    return __uint_as_float(((unsigned)u) << 16);
}
__device__ __forceinline__ u16 f2bf_(float f) {
    __bf16 h = (__bf16)f;
    return __builtin_bit_cast(u16, h);
}
__device__ __forceinline__ void gload_lds16(const void* g, void* l) {
    __builtin_amdgcn_global_load_lds(
        (const __attribute__((address_space(1))) unsigned int*)g,
        (__attribute__((address_space(3))) unsigned int*)l, 16, 0, 0);
}

// ---------------- K0: fp32->bf16 conversions + zero stats ----------------
__global__ void prep(const float* __restrict__ x, const float* __restrict__ wemb,
                     const float* __restrict__ whx, const float* __restrict__ whm,
                     __bf16* __restrict__ xb, __bf16* __restrict__ wembb,
                     __bf16* __restrict__ whxb, __bf16* __restrict__ whmb,
                     float* __restrict__ stats /*2048*/)
{
    long i = (long)blockIdx.x * 256 + threadIdx.x;
    if (i < 2048) stats[i] = 0.0f;
    if (i < 4194304)      xb[i] = (__bf16)x[i];
    else if (i < 4325376) wembb[i - 4194304] = (__bf16)wemb[i - 4194304];
    else if (i < 4521984) whxb[i - 4325376]  = (__bf16)whx[i - 4325376];
    else if (i < 4718592) whmb[i - 4521984]  = (__bf16)whm[i - 4521984];
}

// ---------------- K1: eact GEMM (+bias, LeakyReLU, BN stats), 128x128 tile, BK=32 ----------------
__launch_bounds__(256)
__global__ void gemm_e(const __bf16* __restrict__ A, const __bf16* __restrict__ Bm,
                       const float* __restrict__ bias, __bf16* __restrict__ C,
                       float* __restrict__ sums, float* __restrict__ ssqs,
                       int K, int N)
{
    __shared__ __bf16 As[128 * 32];
    __shared__ __bf16 Bs[128 * 32];
    const int tid  = threadIdx.x;
    const int lane = tid & 63;
    const int wv   = tid >> 6;
    const int wm   = wv >> 1, wn = wv & 1;
    const int l15  = lane & 15, quad = lane >> 4;
    const long m0 = (long)blockIdx.x * 128;
    const long n0 = (long)blockIdx.y * 128;

    const int srow = lane >> 2;
    const int scol = (lane & 3) * 8;
    const __bf16* ag[2]; const __bf16* bg[2];
    __bf16* al[2]; __bf16* bl[2];
#pragma unroll
    for (int j = 0; j < 2; j++) {
        const int s = wv * 2 + j;
        ag[j] = A  + (m0 + s * 16 + srow) * K + scol;
        bg[j] = Bm + (n0 + s * 16 + srow) * K + scol;
        al[j] = &As[s * 512];
        bl[j] = &Bs[s * 512];
    }

    const f32x4 fz = {0.f, 0.f, 0.f, 0.f};
    f32x4 acc[4][4];
#pragma unroll
    for (int i = 0; i < 4; i++)
#pragma unroll
        for (int j = 0; j < 4; j++) acc[i][j] = fz;

    for (int k0 = 0; k0 < K; k0 += 32) {
        __syncthreads();
        gload_lds16(ag[0] + k0, al[0]);
        gload_lds16(ag[1] + k0, al[1]);
        gload_lds16(bg[0] + k0, bl[0]);
        gload_lds16(bg[1] + k0, bl[1]);
        __syncthreads();
        bf16x8 af[4], bfr[4];
#pragma unroll
        for (int mt = 0; mt < 4; mt++)
            af[mt] = *(const bf16x8*)(&As[(wm * 64 + mt * 16 + l15) * 32 + quad * 8]);
#pragma unroll
        for (int nt = 0; nt < 4; nt++)
            bfr[nt] = *(const bf16x8*)(&Bs[(wn * 64 + nt * 16 + l15) * 32 + quad * 8]);
#pragma unroll
        for (int mt = 0; mt < 4; mt++)
#pragma unroll
            for (int nt = 0; nt < 4; nt++)
                acc[mt][nt] = __builtin_amdgcn_mfma_f32_16x16x32_bf16(af[mt], bfr[nt], acc[mt][nt], 0, 0, 0);
    }

#pragma unroll
    for (int nt = 0; nt < 4; nt++) {
        const long ncol = n0 + wn * 64 + nt * 16 + l15;
        const float bi = bias[ncol];
        float s = 0.f, ss = 0.f;
#pragma unroll
        for (int mt = 0; mt < 4; mt++) {
#pragma unroll
            for (int r = 0; r < 4; r++) {
                float v = acc[mt][nt][r] + bi;
                v = (v >= 0.f) ? v : 0.2f * v;
                __bf16 hv = (__bf16)v;
                C[(m0 + wm * 64 + mt * 16 + quad * 4 + r) * (long)N + ncol] = hv;
                float fv = (float)hv; s += fv; ss += fv * fv;
            }
        }
        s += __shfl_xor(s, 16);  ss += __shfl_xor(ss, 16);
        s += __shfl_xor(s, 32);  ss += __shfl_xor(ss, 32);
        if (lane < 16) {
            atomicAdd(&sums[n0 + wn * 64 + nt * 16 + lane], s);
            atomicAdd(&ssqs[n0 + wn * 64 + nt * 16 + lane], ss);
        }
    }
}

// ---------------- K2: build_wp (blocks 0..767) + build_gim (blocks 768..3839) merged ----------------
__global__ void build_misc(const float* __restrict__ w_ih_x, const float* __restrict__ b_ih_x,
                           const float* __restrict__ b_hh_x, const float* __restrict__ sums,
                           const float* __restrict__ ssqs, const float* __restrict__ gamma,
                           const float* __restrict__ beta, __bf16* __restrict__ wpx,
                           float* __restrict__ biasx,
                           const float* __restrict__ memory, const float* __restrict__ w_ih_m,
                           const float* __restrict__ b_ih_m, const float* __restrict__ b_hh_m,
                           __bf16* __restrict__ gim)
{
    const int lane = threadIdx.x;  // 64
    if (blockIdx.x < 768) {
        const int j = blockIdx.x;
        const float inv = 1.0f / 32768.0f;
        float accv = 0.f;
#pragma unroll
        for (int i = 0; i < 16; i++) {
            int h = i * 64 + lane;
            float mean = sums[h] * inv;
            float var  = ssqs[h] * inv - mean * mean;
            float s    = rsqrtf(var + 1e-5f) * gamma[h];
            float c    = beta[h] - mean * s;
            float w = w_ih_x[(long)j * 1024 + h];
            wpx[(long)j * 1024 + h] = (__bf16)(w * s);
            accv += c * w;
        }
        for (int off = 32; off; off >>= 1) accv += __shfl_xor(accv, off);
        if (lane == 0) biasx[j] = accv + b_ih_x[j] + (j < 512 ? b_hh_x[j] : 0.0f);
    } else {
        const int g  = blockIdx.x - 768;
        const int jj = g % 768;
        const int t0 = (g / 768) * 32;
        float w[16];
#pragma unroll
        for (int i = 0; i < 16; i++) w[i] = w_ih_m[(long)jj * 1024 + i * 64 + lane];
        const float bb = b_ih_m[jj] + (jj < 512 ? b_hh_m[jj] : 0.0f);
        for (int t = t0; t < t0 + 32; t++) {
            float s = 0.f;
#pragma unroll
            for (int i = 0; i < 16; i++) s += w[i] * memory[(long)t * 1024 + i * 64 + lane];
            for (int off = 32; off; off >>= 1) s += __shfl_xor(s, off);
            if (lane == 0) gim[t * 768 + jj] = (__bf16)(s + bb);
        }
    }
}

// ---------------- K3: gi GEMM producing gperm v2, 128x384 tiles ----------------
// blockIdx g: mt = g>>1 (t = mt>>1, bhalf = mt&1), nh = g&1 (384-col half).
// gperm v2 u16 index: (((t*16 + wg)*8 + v)*3 + gate)*512 + lane*8 + (r*2 + ct)
// -> producer store per (i,jp): 64 lanes x 16 B CONTIGUOUS (coalesced).
__launch_bounds__(512, 2)
__global__ void gemm_gi(const __bf16* __restrict__ eact, const __bf16* __restrict__ wpx,
                        const float* __restrict__ biasx, __bf16* __restrict__ gperm)
{
    __shared__ __bf16 As[128 * 32];
    __shared__ __bf16 Bs[384 * 32];
    const int tid  = threadIdx.x;
    const int lane = tid & 63;
    const int v    = tid >> 6;
    const int l15  = lane & 15, quad = lane >> 4;

    const int g   = blockIdx.x;        // 0..511
    const int mt  = g >> 1;
    const int nh  = g & 1;
    const int t   = mt >> 1, bhalf = mt & 1;
    const int c0  = nh * 384;
    const int mh  = v >> 2, q = v & 3; // wave: rows mh*64+.., cols q*96+..
    const int srow = lane >> 2, scol = (lane & 3) * 8;

    const __bf16* agA = eact + ((long)(bhalf * 128 + v * 16 + srow) * 128 + t) * 1024 + scol;
    __bf16* alA = &As[v * 512];
    const __bf16* agB[3]; __bf16* blB[3];
#pragma unroll
    for (int sub = 0; sub < 3; sub++) {
        agB[sub] = wpx + (long)(c0 + v * 48 + sub * 16 + srow) * 1024 + scol;
        blB[sub] = &Bs[(v * 3 + sub) * 512];
    }

    const f32x4 fz = {0.f, 0.f, 0.f, 0.f};
    f32x4 acc[4][6];
#pragma unroll
    for (int i = 0; i < 4; i++)
#pragma unroll
        for (int j = 0; j < 6; j++) acc[i][j] = fz;

    for (int k0 = 0; k0 < 1024; k0 += 32) {
        __syncthreads();
        gload_lds16(agA + k0, alA);
        gload_lds16(agB[0] + k0, blB[0]);
        gload_lds16(agB[1] + k0, blB[1]);
        gload_lds16(agB[2] + k0, blB[2]);
        __syncthreads();
        bf16x8 af[4], bfr[6];
#pragma unroll
        for (int i = 0; i < 4; i++)
            af[i] = *(const bf16x8*)(&As[(mh * 64 + i * 16 + l15) * 32 + quad * 8]);
#pragma unroll
        for (int j = 0; j < 6; j++)
            bfr[j] = *(const bf16x8*)(&Bs[(q * 96 + j * 16 + l15) * 32 + quad * 8]);
#pragma unroll
        for (int i = 0; i < 4; i++)
#pragma unroll
            for (int j = 0; j < 6; j++)
                acc[i][j] = __builtin_amdgcn_mfma_f32_16x16x32_bf16(af[i], bfr[j], acc[i][j], 0, 0, 0);
    }

    float bi[6];
#pragma unroll
    for (int j = 0; j < 6; j++) bi[j] = biasx[c0 + q * 96 + j * 16 + l15];

    u16* gp = (u16*)gperm;
#pragma unroll
    for (int i = 0; i < 4; i++) {
        const int wgi = bhalf * 8 + mh * 4 + i;
#pragma unroll
        for (int jp = 0; jp < 3; jp++) {
            const int cbase = c0 + q * 96 + jp * 32;
            const int gg = cbase >> 8;             // gate
            const int vc = (cbase >> 5) & 7;       // consumer wave
            unsigned wbits[4];
#pragma unroll
            for (int r = 0; r < 4; r++) {
                u16 lo = f2bf_(acc[i][2 * jp + 0][r] + bi[2 * jp + 0]);
                u16 hi = f2bf_(acc[i][2 * jp + 1][r] + bi[2 * jp + 1]);
                wbits[r] = (unsigned)lo | ((unsigned)hi << 16);
            }
            uint4 o = {wbits[0], wbits[1], wbits[2], wbits[3]};
            const long idx = ((((long)t * 16 + wgi) * 8 + vc) * 3 + gg) * 512 + (long)lane * 8;
            *(uint4*)(gp + idx) = o;
        }
    }
}

// ---------------- K4: GRU recurrence (R3 structure + gperm-v2 gate path) ----------------
// wg 0..15: 16 batch rows; wg 16: hm (batch-uniform, scalar register prefetch from gim).
// 8 waves; one __syncthreads/step; gil double-buffered, staged by 3 coalesced global_load_lds
// per wave; gate phase = 3 ds_read_b128 + shift-unpack. MFMA split ct0-pass / ct1-pass.
__launch_bounds__(512, 2)
__global__ void recurrence(const __bf16* __restrict__ gperm, const __bf16* __restrict__ gim,
                           const __bf16* __restrict__ whx, const __bf16* __restrict__ whm,
                           const float* __restrict__ bhhx, const float* __restrict__ bhhm,
                           float* __restrict__ hxfin, float* __restrict__ hmfin)
{
    __shared__ __bf16 hxl[2][16 * 264];     // 16,896 B
    __shared__ __bf16 gil[2][8][3][512];    // 49,152 B (per buf: wave x gate x 1KB lane-linear)
    const int tid  = threadIdx.x;
    const int lane = tid & 63;
    const int v    = tid >> 6;     // wave 0..7
    const int l15  = lane & 15, quad = lane >> 4;
    const int wg   = blockIdx.x;   // 0..16
    const bool isX = (wg < 16);
    const __bf16* wh  = isX ? whx : whm;
    const float*  bhh = isX ? bhhx : bhhm;

    // W[nt]: nt = gate*2 + ct; wave v owns cols [32v,32v+32) of each gate
    bf16x8 W[6][8];
#pragma unroll
    for (int nt = 0; nt < 6; nt++) {
        const int gg = nt >> 1, ct = nt & 1;
        const long j = gg * 256 + (v * 2 + ct) * 16 + l15;
#pragma unroll
        for (int kt = 0; kt < 8; kt++)
            W[nt][kt] = *(const bf16x8*)(wh + j * 256 + kt * 32 + quad * 8);
    }
    float bhhn[2];
#pragma unroll
    for (int ct = 0; ct < 2; ct++) bhhn[ct] = bhh[512 + v * 32 + ct * 16 + l15];

    for (int i = tid; i < 16 * 264; i += 512) hxl[0][i] = (__bf16)0.f;

    float st[8];
#pragma unroll
    for (int i = 0; i < 8; i++) st[i] = 0.f;

    // gperm base for this (wg, v): u16 elems; per-t stride = 16*8*3*512 = 196608
    const __bf16* gpb = gperm + (((long)wg * 8 + v) * 3) * 512;
    const u16*    gmb = (const u16*)gim + (v * 32 + l15);
    u16 hc0 = 0, hc1 = 0, hc2 = 0, hc3 = 0, hc4 = 0, hc5 = 0;   // hm cur (g*2+ct)
    u16 hn0 = 0, hn1 = 0, hn2 = 0, hn3 = 0, hn4 = 0, hn5 = 0;   // hm next

    // prologue: stage t=0 into buf 0
    if (isX) {
        gload_lds16(gpb + lane * 8,        &gil[0][v][0][0]);
        gload_lds16(gpb + 512 + lane * 8,  &gil[0][v][1][0]);
        gload_lds16(gpb + 1024 + lane * 8, &gil[0][v][2][0]);
    } else {
        hc0 = gmb[0]; hc1 = gmb[16]; hc2 = gmb[256]; hc3 = gmb[272]; hc4 = gmb[512]; hc5 = gmb[528];
    }
    __syncthreads();   // hxl[0] zero + gil[0] staged (vmcnt drained)

    for (int t = 0; t < 128; t++) {
        const int bi = t & 1;
        // stage t+1 into buf bi^1
        if (t + 1 < 128) {
            if (isX) {
                const __bf16* src = gpb + (long)(t + 1) * 196608;
                gload_lds16(src + lane * 8,        &gil[bi ^ 1][v][0][0]);
                gload_lds16(src + 512 + lane * 8,  &gil[bi ^ 1][v][1][0]);
                gload_lds16(src + 1024 + lane * 8, &gil[bi ^ 1][v][2][0]);
            } else {
                const u16* p = gmb + (long)(t + 1) * 768;
                hn0 = p[0]; hn1 = p[16]; hn2 = p[256]; hn3 = p[272]; hn4 = p[512]; hn5 = p[528];
            }
        }

        const f32x4 fz = {0.f, 0.f, 0.f, 0.f};
        f32x4 acc[6];
#pragma unroll
        for (int nt = 0; nt < 6; nt++) acc[nt] = fz;
        const __bf16* hxc = &hxl[bi][0];
        // pass 1: ct=0 tiles (r,z,n)
#pragma unroll
        for (int kt = 0; kt < 8; kt++) {
            bf16x8 a = *(const bf16x8*)(hxc + l15 * 264 + kt * 32 + quad * 8);
            acc[0] = __builtin_amdgcn_mfma_f32_16x16x32_bf16(a, W[0][kt], acc[0], 0, 0, 0);
            acc[2] = __builtin_amdgcn_mfma_f32_16x16x32_bf16(a, W[2][kt], acc[2], 0, 0, 0);
            acc[4] = __builtin_amdgcn_mfma_f32_16x16x32_bf16(a, W[4][kt], acc[4], 0, 0, 0);
        }
        // pass 2: ct=1 tiles
#pragma unroll
        for (int kt = 0; kt < 8; kt++) {
            bf16x8 a = *(const bf16x8*)(hxc + l15 * 264 + kt * 32 + quad * 8);
            acc[1] = __builtin_amdgcn_mfma_f32_16x16x32_bf16(a, W[1][kt], acc[1], 0, 0, 0);
            acc[3] = __builtin_amdgcn_mfma_f32_16x16x32_bf16(a, W[3][kt], acc[3], 0, 0, 0);
            acc[5] = __builtin_amdgcn_mfma_f32_16x16x32_bf16(a, W[5][kt], acc[5], 0, 0, 0);
        }

        // gate inputs: 3 x ds_read_b128, lane-linear (conflict-free canonical pattern)
        uint4 qr = {0,0,0,0}, qz = {0,0,0,0}, qn = {0,0,0,0};
        if (isX) {
            qr = ((const uint4*)&gil[bi][v][0][0])[lane];
            qz = ((const uint4*)&gil[bi][v][1][0])[lane];
            qn = ((const uint4*)&gil[bi][v][2][0])[lane];
        }
        __bf16* hxn = &hxl[bi ^ 1][0];

        // ct = 0 gates (overlaps pass-2 MFMA drain)
#pragma unroll
        for (int r = 0; r < 4; r++) {
            const unsigned ur = (r == 0) ? qr.x : (r == 1) ? qr.y : (r == 2) ? qr.z : qr.w;
            const unsigned uz = (r == 0) ? qz.x : (r == 1) ? qz.y : (r == 2) ? qz.z : qz.w;
            const unsigned un = (r == 0) ? qn.x : (r == 1) ? qn.y : (r == 2) ? qn.z : qn.w;
            const float gr = isX ? __uint_as_float(ur << 16) : bf16bits_(hc0);
            const float gz = isX ? __uint_as_float(uz << 16) : bf16bits_(hc2);
            const float gn = isX ? __uint_as_float(un << 16) : bf16bits_(hc4);
            const float rg = sigmoidf_(gr + acc[0][r]);
            const float zg = sigmoidf_(gz + acc[2][r]);
            const float ng = tanhf_(gn + rg * (acc[4][r] + bhhn[0]));
            float h = st[r];
            h = ng + zg * (h - ng);
            st[r] = h;
            hxn[(quad * 4 + r) * 264 + v * 32 + l15] = (__bf16)h;
        }
        // ct = 1 gates
#pragma unroll
        for (int r = 0; r < 4; r++) {
            const unsigned ur = (r == 0) ? qr.x : (r == 1) ? qr.y : (r == 2) ? qr.z : qr.w;
            const unsigned uz = (r == 0) ? qz.x : (r == 1) ? qz.y : (r == 2) ? qz.z : qz.w;
            const unsigned un = (r == 0) ? qn.x : (r == 1) ? qn.y : (r == 2) ? qn.z : qn.w;
            const float gr = isX ? __uint_as_float(ur & 0xffff0000u) : bf16bits_(hc1);
            const float gz = isX ? __uint_as_float(uz & 0xffff0000u) : bf16bits_(hc3);
            const float gn = isX ? __uint_as_float(un & 0xffff0000u) : bf16bits_(hc5);
            const float rg = sigmoidf_(gr + acc[1][r]);
            const float zg = sigmoidf_(gz + acc[3][r]);
            const float ng = tanhf_(gn + rg * (acc[5][r] + bhhn[1]));
            float h = st[4 + r];
            h = ng + zg * (h - ng);
            st[4 + r] = h;
            hxn[(quad * 4 + r) * 264 + v * 32 + 16 + l15] = (__bf16)h;
        }
        if (!isX) { hc0 = hn0; hc1 = hn1; hc2 = hn2; hc3 = hn3; hc4 = hn4; hc5 = hn5; }
        __syncthreads();   // hx visible + gil[bi^1] staged (vmcnt drained)
    }

    float* finp = isX ? (hxfin + (long)wg * 16 * 256) : hmfin;
#pragma unroll
    for (int ct = 0; ct < 2; ct++) {
        const int ob = v * 32 + ct * 16 + l15;
#pragma unroll
        for (int r = 0; r < 4; r++)
            finp[(quad * 4 + r) * 256 + ob] = st[ct * 4 + r];
    }
}

// ---------------- K5: cosine gate at t=T-1 -> output ----------------
__global__ void finalize(const float* __restrict__ hxfin, const float* __restrict__ hmfin,
                         const float* __restrict__ W_sx, const float* __restrict__ b_sx,
                         const float* __restrict__ W_sm, const float* __restrict__ b_sm,
                         float* __restrict__ out)
{
    const int b = blockIdx.x;      // 256
    const int lane = threadIdx.x;  // 64
    float qx[4], qm[4];
#pragma unroll
    for (int s = 0; s < 4; s++) {
        float px = 0.f, pm = 0.f;
#pragma unroll
        for (int i = 0; i < 4; i++) {
            int h = i * 64 + lane;
            px += W_sx[s * 256 + h] * hxfin[b * 256 + h];
            pm += W_sm[s * 256 + h] * hmfin[h];
        }
        for (int off = 32; off; off >>= 1) { px += __shfl_xor(px, off); pm += __shfl_xor(pm, off); }
        qx[s] = px + b_sx[s];
        qm[s] = pm + b_sm[s];
    }
    float num = 0.f, nx = 0.f, nm = 0.f;
#pragma unroll
    for (int s = 0; s < 4; s++) { num += qx[s] * qm[s]; nx += qx[s] * qx[s]; nm += qm[s] * qm[s]; }
    const float den = fmaxf(sqrtf(nx), 1e-8f) * fmaxf(sqrtf(nm), 1e-8f);
    const float g = 1.0f / (1.0f + __expf(-num / den));
#pragma unroll
    for (int i = 0; i < 4; i++) {
        int h = i * 64 + lane;
        out[b * 256 + h] = g * hxfin[b * 256 + h] + (1.0f - g) * hmfin[h];
    }
}

extern "C" void kernel_launch(void* const* d_in, const int* in_sizes, int n_in,
                              void* d_out, int out_size, void* d_ws, size_t ws_size,
                              hipStream_t stream)
{
    (void)in_sizes; (void)n_in; (void)out_size; (void)ws_size;
    const float* x      = (const float*)d_in[0];
    const float* W_emb  = (const float*)d_in[1];
    const float* b_emb  = (const float*)d_in[2];
    const float* gamma  = (const float*)d_in[3];
    const float* beta   = (const float*)d_in[4];
    const float* memory = (const float*)d_in[5];
    const float* w_ih_x = (const float*)d_in[6];
    const float* w_hh_x = (const float*)d_in[7];
    const float* b_ih_x = (const float*)d_in[8];
    const float* b_hh_x = (const float*)d_in[9];
    const float* w_ih_m = (const float*)d_in[10];
    const float* w_hh_m = (const float*)d_in[11];
    const float* b_ih_m = (const float*)d_in[12];
    const float* b_hh_m = (const float*)d_in[13];
    const float* W_sx   = (const float*)d_in[14];
    const float* b_sx   = (const float*)d_in[15];
    const float* W_sm   = (const float*)d_in[16];
    const float* b_sm   = (const float*)d_in[17];
    float* out = (float*)d_out;
    char* ws = (char*)d_ws;

    __bf16* xb    = (__bf16*)(ws + OFF_XB);
    __bf16* wembb = (__bf16*)(ws + OFF_WEMB);
    __bf16* whxb  = (__bf16*)(ws + OFF_WHX);
    __bf16* whmb  = (__bf16*)(ws + OFF_WHM);
    float*  sums  = (float*)(ws + OFF_SUM);
    float*  ssqs  = (float*)(ws + OFF_SSQ);
    float*  biasx = (float*)(ws + OFF_BIASX);
    __bf16* gim   = (__bf16*)(ws + OFF_GIM);
    __bf16* eact  = (__bf16*)(ws + OFF_EACT);
    __bf16* gperm = (__bf16*)(ws + OFF_GI);
    float*  hxf   = (float*)(ws + OFF_HXF);
    float*  hmf   = (float*)(ws + OFF_HMF);
    __bf16* wpx   = (__bf16*)(ws + OFF_WPX);

    prep<<<18432, 256, 0, stream>>>(x, W_emb, w_hh_x, w_hh_m, xb, wembb, whxb, whmb, sums);
    gemm_e<<<dim3(256, 8), 256, 0, stream>>>(xb, wembb, b_emb, eact, sums, ssqs, 128, 1024);
    build_misc<<<3840, 64, 0, stream>>>(w_ih_x, b_ih_x, b_hh_x, sums, ssqs, gamma, beta, wpx, biasx,
                                        memory, w_ih_m, b_ih_m, b_hh_m, gim);
    gemm_gi<<<512, 512, 0, stream>>>(eact, wpx, biasx, gperm);
    recurrence<<<17, 512, 0, stream>>>(gperm, gim, whxb, whmb, b_hh_x, b_hh_m, hxf, hmf);
    finalize<<<256, 64, 0, stream>>>(hxf, hmf, W_sx, b_sx, W_sm, b_sm, out);
}

// Round 10
// 552.431 us; speedup vs baseline: 1.1738x; 1.1587x over previous
//
#include <hip/hip_runtime.h>
#include <stdint.h>

// MemoryDiscriminator: embed-GEMM + LeakyReLU + BN(fold into GEMM2) + dual GRU scan + cosine gate.
// Key identities: hm is batch-uniform; only t=T-1 output needed; gi_x hoisted out of scan.
// R10: recurrence + gi[b][t] layout reverted to R3 VERBATIM (proven 247 us; R5-R9 showed every
//      alternative gate-source layout/protocol is slower -- sequential per-wave streams win).
//      gi GEMM upgraded to 256x384 tiles (gemm_gi3): HBM tile traffic 786 MB -> 327 MB.

typedef float  f32x4 __attribute__((ext_vector_type(4)));
typedef __bf16 bf16x8 __attribute__((ext_vector_type(8)));

// ---------------- workspace layout (bytes) ----------------
static constexpr size_t OFF_XB    = 0;          // 32768*128 bf16   = 8,388,608
static constexpr size_t OFF_WEMB  = 8388608;    // 1024*128 bf16    = 262,144
static constexpr size_t OFF_WHX   = 8650752;    // 768*256 bf16     = 393,216
static constexpr size_t OFF_WHM   = 9043968;    // 768*256 bf16     = 393,216
static constexpr size_t OFF_SUM   = 9437184;    // 1024 f32
static constexpr size_t OFF_SSQ   = 9441280;    // 1024 f32
static constexpr size_t OFF_BIASX = 9453568;    // 768 f32 (padded)
static constexpr size_t OFF_GIM   = 9457664;    // 128*768 bf16     = 196,608
static constexpr size_t OFF_EACT  = 9654272;    // 32768*1024 bf16  = 67,108,864
static constexpr size_t OFF_GI    = 76763136;   // 32768*768 bf16 [b][t][768] = 50,331,648
static constexpr size_t OFF_HXF   = 127094784;  // 256*256 f32
static constexpr size_t OFF_HMF   = 127356928;  // 16*256 f32
static constexpr size_t OFF_WPX   = 127373312;  // 768*1024 bf16    = 1,572,864
// total ~128.9 MB

__device__ __forceinline__ float sigmoidf_(float x) {
    return __builtin_amdgcn_rcpf(1.0f + __expf(-x));
}
__device__ __forceinline__ float tanhf_(float x) {
    return 1.0f - 2.0f * __builtin_amdgcn_rcpf(1.0f + __expf(2.0f * x));
}
__device__ __forceinline__ void gload_lds16(const void* g, void* l) {
    __builtin_amdgcn_global_load_lds(
        (const __attribute__((address_space(1))) unsigned int*)g,
        (__attribute__((address_space(3))) unsigned int*)l, 16, 0, 0);
}

// ---------------- K0: fp32->bf16 conversions + zero stats ----------------
__global__ void prep(const float* __restrict__ x, const float* __restrict__ wemb,
                     const float* __restrict__ whx, const float* __restrict__ whm,
                     __bf16* __restrict__ xb, __bf16* __restrict__ wembb,
                     __bf16* __restrict__ whxb, __bf16* __restrict__ whmb,
                     float* __restrict__ stats /*2048*/)
{
    long i = (long)blockIdx.x * 256 + threadIdx.x;
    if (i < 2048) stats[i] = 0.0f;
    if (i < 4194304)      xb[i] = (__bf16)x[i];
    else if (i < 4325376) wembb[i - 4194304] = (__bf16)wemb[i - 4194304];
    else if (i < 4521984) whxb[i - 4325376]  = (__bf16)whx[i - 4325376];
    else if (i < 4718592) whmb[i - 4521984]  = (__bf16)whm[i - 4521984];
}

// ---------------- K1: eact GEMM (+bias, LeakyReLU, BN stats), 128x128 tile, BK=32 ----------------
__launch_bounds__(256)
__global__ void gemm_e(const __bf16* __restrict__ A, const __bf16* __restrict__ Bm,
                       const float* __restrict__ bias, __bf16* __restrict__ C,
                       float* __restrict__ sums, float* __restrict__ ssqs,
                       int K, int N)
{
    __shared__ __bf16 As[128 * 32];
    __shared__ __bf16 Bs[128 * 32];
    const int tid  = threadIdx.x;
    const int lane = tid & 63;
    const int wv   = tid >> 6;
    const int wm   = wv >> 1, wn = wv & 1;
    const int l15  = lane & 15, quad = lane >> 4;
    const long m0 = (long)blockIdx.x * 128;
    const long n0 = (long)blockIdx.y * 128;

    const int srow = lane >> 2;
    const int scol = (lane & 3) * 8;
    const __bf16* ag[2]; const __bf16* bg[2];
    __bf16* al[2]; __bf16* bl[2];
#pragma unroll
    for (int j = 0; j < 2; j++) {
        const int s = wv * 2 + j;
        ag[j] = A  + (m0 + s * 16 + srow) * K + scol;
        bg[j] = Bm + (n0 + s * 16 + srow) * K + scol;
        al[j] = &As[s * 512];
        bl[j] = &Bs[s * 512];
    }

    const f32x4 fz = {0.f, 0.f, 0.f, 0.f};
    f32x4 acc[4][4];
#pragma unroll
    for (int i = 0; i < 4; i++)
#pragma unroll
        for (int j = 0; j < 4; j++) acc[i][j] = fz;

    for (int k0 = 0; k0 < K; k0 += 32) {
        __syncthreads();
        gload_lds16(ag[0] + k0, al[0]);
        gload_lds16(ag[1] + k0, al[1]);
        gload_lds16(bg[0] + k0, bl[0]);
        gload_lds16(bg[1] + k0, bl[1]);
        __syncthreads();
        bf16x8 af[4], bfr[4];
#pragma unroll
        for (int mt = 0; mt < 4; mt++)
            af[mt] = *(const bf16x8*)(&As[(wm * 64 + mt * 16 + l15) * 32 + quad * 8]);
#pragma unroll
        for (int nt = 0; nt < 4; nt++)
            bfr[nt] = *(const bf16x8*)(&Bs[(wn * 64 + nt * 16 + l15) * 32 + quad * 8]);
#pragma unroll
        for (int mt = 0; mt < 4; mt++)
#pragma unroll
            for (int nt = 0; nt < 4; nt++)
                acc[mt][nt] = __builtin_amdgcn_mfma_f32_16x16x32_bf16(af[mt], bfr[nt], acc[mt][nt], 0, 0, 0);
    }

#pragma unroll
    for (int nt = 0; nt < 4; nt++) {
        const long ncol = n0 + wn * 64 + nt * 16 + l15;
        const float bi = bias[ncol];
        float s = 0.f, ss = 0.f;
#pragma unroll
        for (int mt = 0; mt < 4; mt++) {
#pragma unroll
            for (int r = 0; r < 4; r++) {
                float v = acc[mt][nt][r] + bi;
                v = (v >= 0.f) ? v : 0.2f * v;
                __bf16 hv = (__bf16)v;
                C[(m0 + wm * 64 + mt * 16 + quad * 4 + r) * (long)N + ncol] = hv;
                float fv = (float)hv; s += fv; ss += fv * fv;
            }
        }
        s += __shfl_xor(s, 16);  ss += __shfl_xor(ss, 16);
        s += __shfl_xor(s, 32);  ss += __shfl_xor(ss, 32);
        if (lane < 16) {
            atomicAdd(&sums[n0 + wn * 64 + nt * 16 + lane], s);
            atomicAdd(&ssqs[n0 + wn * 64 + nt * 16 + lane], ss);
        }
    }
}

// ---------------- K2: build_wp (blocks 0..767) + build_gim (blocks 768..3839) merged ----------------
__global__ void build_misc(const float* __restrict__ w_ih_x, const float* __restrict__ b_ih_x,
                           const float* __restrict__ b_hh_x, const float* __restrict__ sums,
                           const float* __restrict__ ssqs, const float* __restrict__ gamma,
                           const float* __restrict__ beta, __bf16* __restrict__ wpx,
                           float* __restrict__ biasx,
                           const float* __restrict__ memory, const float* __restrict__ w_ih_m,
                           const float* __restrict__ b_ih_m, const float* __restrict__ b_hh_m,
                           __bf16* __restrict__ gim)
{
    const int lane = threadIdx.x;  // 64
    if (blockIdx.x < 768) {
        const int j = blockIdx.x;
        const float inv = 1.0f / 32768.0f;
        float accv = 0.f;
#pragma unroll
        for (int i = 0; i < 16; i++) {
            int h = i * 64 + lane;
            float mean = sums[h] * inv;
            float var  = ssqs[h] * inv - mean * mean;
            float s    = rsqrtf(var + 1e-5f) * gamma[h];
            float c    = beta[h] - mean * s;
            float w = w_ih_x[(long)j * 1024 + h];
            wpx[(long)j * 1024 + h] = (__bf16)(w * s);
            accv += c * w;
        }
        for (int off = 32; off; off >>= 1) accv += __shfl_xor(accv, off);
        if (lane == 0) biasx[j] = accv + b_ih_x[j] + (j < 512 ? b_hh_x[j] : 0.0f);
    } else {
        const int g  = blockIdx.x - 768;
        const int jj = g % 768;
        const int t0 = (g / 768) * 32;
        float w[16];
#pragma unroll
        for (int i = 0; i < 16; i++) w[i] = w_ih_m[(long)jj * 1024 + i * 64 + lane];
        const float bb = b_ih_m[jj] + (jj < 512 ? b_hh_m[jj] : 0.0f);
        for (int t = t0; t < t0 + 32; t++) {
            float s = 0.f;
#pragma unroll
            for (int i = 0; i < 16; i++) s += w[i] * memory[(long)t * 1024 + i * 64 + lane];
            for (int off = 32; off; off >>= 1) s += __shfl_xor(s, off);
            if (lane == 0) gim[t * 768 + jj] = (__bf16)(s + bb);
        }
    }
}

// ---------------- K3: gi GEMM, 256x384 tile, BK=32, 16 waves (m97 staging) ----------------
// C = gi[b][t] layout: row m = b*128+t (same as eact row index). Grid (128, 2).
__launch_bounds__(1024)
__global__ void gemm_gi3(const __bf16* __restrict__ A, const __bf16* __restrict__ Bm,
                         const float* __restrict__ bias, __bf16* __restrict__ C)
{
    __shared__ __bf16 As[256 * 32];   // 16 KB
    __shared__ __bf16 Bs[384 * 32];   // 24 KB
    const int tid  = threadIdx.x;
    const int lane = tid & 63;
    const int v    = tid >> 6;        // wave 0..15
    const int l15  = lane & 15, quad = lane >> 4;
    const int wm   = v >> 2, wn = v & 3;   // wave tile: rows wm*64+[0,64), cols wn*96+[0,96)
    const long m0 = (long)blockIdx.x * 256;
    const long n0 = (long)blockIdx.y * 384;

    const int srow = lane >> 2;
    const int scol = (lane & 3) * 8;
    // staging: wave v -> As rows [v*16, v*16+16); Bs rows [v*16,..); waves 0..7 also Bs rows [256+v*16,..)
    const __bf16* ag  = A  + (m0 + v * 16 + srow) * 1024 + scol;
    __bf16*       al  = &As[v * 512];
    const __bf16* bg0 = Bm + (n0 + v * 16 + srow) * 1024 + scol;
    __bf16*       bl0 = &Bs[v * 512];
    const __bf16* bg1 = Bm + (n0 + 256 + v * 16 + srow) * 1024 + scol;
    __bf16*       bl1 = &Bs[(16 + v) * 512];

    const f32x4 fz = {0.f, 0.f, 0.f, 0.f};
    f32x4 acc[4][6];
#pragma unroll
    for (int i = 0; i < 4; i++)
#pragma unroll
        for (int j = 0; j < 6; j++) acc[i][j] = fz;

    for (int k0 = 0; k0 < 1024; k0 += 32) {
        __syncthreads();
        gload_lds16(ag + k0, al);
        gload_lds16(bg0 + k0, bl0);
        if (v < 8) gload_lds16(bg1 + k0, bl1);
        __syncthreads();
        bf16x8 af[4], bfr[6];
#pragma unroll
        for (int i = 0; i < 4; i++)
            af[i] = *(const bf16x8*)(&As[(wm * 64 + i * 16 + l15) * 32 + quad * 8]);
#pragma unroll
        for (int j = 0; j < 6; j++)
            bfr[j] = *(const bf16x8*)(&Bs[(wn * 96 + j * 16 + l15) * 32 + quad * 8]);
#pragma unroll
        for (int i = 0; i < 4; i++)
#pragma unroll
            for (int j = 0; j < 6; j++)
                acc[i][j] = __builtin_amdgcn_mfma_f32_16x16x32_bf16(af[i], bfr[j], acc[i][j], 0, 0, 0);
    }

#pragma unroll
    for (int j = 0; j < 6; j++) {
        const long ncol = n0 + wn * 96 + j * 16 + l15;
        const float bi = bias[ncol];
#pragma unroll
        for (int i = 0; i < 4; i++)
#pragma unroll
            for (int r = 0; r < 4; r++)
                C[(m0 + wm * 64 + i * 16 + quad * 4 + r) * 768 + ncol] =
                    (__bf16)(acc[i][j][r] + bi);
    }
}

// ---------------- K4: GRU recurrence (R3 VERBATIM -- proven 247 us) ----------------
// wg 0..15: 16 batch rows each; wg 16: hm (batch-uniform). One barrier/step; gi[t+1]
// prefetched into double-buffered gil via global_load_lds; gates read as 24 ds_read_u16.
__launch_bounds__(512, 2)
__global__ void recurrence(const __bf16* __restrict__ gi, const __bf16* __restrict__ gim,
                           const __bf16* __restrict__ whx, const __bf16* __restrict__ whm,
                           const float* __restrict__ bhhx, const float* __restrict__ bhhm,
                           float* __restrict__ hxfin, float* __restrict__ hmfin)
{
    __shared__ __bf16 hxl[2][16 * 264];
    __shared__ __bf16 gil[2][16 * 776];
    const int wg   = blockIdx.x;   // 0..16
    const int tid  = threadIdx.x;
    const int lane = tid & 63;
    const int v    = tid >> 6;     // wave 0..7
    const int l15  = lane & 15, quad = lane >> 4;
    const bool isX = (wg < 16);
    const __bf16* wh    = isX ? whx : whm;
    const float*  bhh   = isX ? bhhx : bhhm;
    const __bf16* gbase = isX ? gi : gim;

    bf16x8 W[6][8];
#pragma unroll
    for (int nt = 0; nt < 6; nt++) {
        const int g = nt >> 1, ct = nt & 1;
        const long j = g * 256 + (v * 2 + ct) * 16 + l15;
#pragma unroll
        for (int kt = 0; kt < 8; kt++)
            W[nt][kt] = *(const bf16x8*)(wh + j * 256 + kt * 32 + quad * 8);
    }
    float bhhn[2];
#pragma unroll
    for (int ct = 0; ct < 2; ct++) bhhn[ct] = bhh[512 + v * 32 + ct * 16 + l15];

    for (int i = tid; i < 16 * 264; i += 512) hxl[0][i] = (__bf16)0.f;

    float st[8];
#pragma unroll
    for (int i = 0; i < 8; i++) st[i] = 0.f;

    const int r0 = v * 2, r1 = r0 + 1;
    const long grow0 = isX ? (long)((wg * 16 + r0) * 128) * 768 : 0;
    const long grow1 = isX ? (long)((wg * 16 + r1) * 128) * 768 : 0;

    {
        const __bf16* p0 = gbase + grow0;
        const __bf16* p1 = gbase + grow1;
        gload_lds16(p0 + (long)lane * 8, &gil[0][r0 * 776]);
        gload_lds16(p1 + (long)lane * 8, &gil[0][r1 * 776]);
        if (lane < 32) {
            gload_lds16(p0 + 512 + (long)lane * 8, &gil[0][r0 * 776 + 512]);
            gload_lds16(p1 + 512 + (long)lane * 8, &gil[0][r1 * 776 + 512]);
        }
    }
    __syncthreads();

    int cur = 0;
    for (int t = 0; t < 128; t++) {
        if (t < 127) {
            const __bf16* p0 = gbase + grow0 + (long)(t + 1) * 768;
            const __bf16* p1 = gbase + grow1 + (long)(t + 1) * 768;
            __bf16* dst = &gil[(t + 1) & 1][0];
            gload_lds16(p0 + (long)lane * 8, dst + r0 * 776);
            gload_lds16(p1 + (long)lane * 8, dst + r1 * 776);
            if (lane < 32) {
                gload_lds16(p0 + 512 + (long)lane * 8, dst + r0 * 776 + 512);
                gload_lds16(p1 + 512 + (long)lane * 8, dst + r1 * 776 + 512);
            }
        }

        const f32x4 fz = {0.f, 0.f, 0.f, 0.f};
        f32x4 acc[6];
#pragma unroll
        for (int nt = 0; nt < 6; nt++) acc[nt] = fz;
        const __bf16* hxc = &hxl[cur][0];
#pragma unroll
        for (int kt = 0; kt < 8; kt++) {
            bf16x8 a = *(const bf16x8*)(hxc + l15 * 264 + kt * 32 + quad * 8);
#pragma unroll
            for (int nt = 0; nt < 6; nt++)
                acc[nt] = __builtin_amdgcn_mfma_f32_16x16x32_bf16(a, W[nt][kt], acc[nt], 0, 0, 0);
        }

        const int nxt = cur ^ 1;
        __bf16* hxn = &hxl[nxt][0];
        const __bf16* gcur = &gil[t & 1][0];
#pragma unroll
        for (int ct = 0; ct < 2; ct++) {
            const int ob = v * 32 + ct * 16 + l15;
#pragma unroll
            for (int r = 0; r < 4; r++) {
                const int row = quad * 4 + r;   // C/D layout: row = quad*4+reg, col = lane&15
                const float gr = (float)gcur[row * 776 + ob];
                const float gz = (float)gcur[row * 776 + 256 + ob];
                const float gn = (float)gcur[row * 776 + 512 + ob];
                const float rg = sigmoidf_(gr + acc[ct][r]);
                const float zg = sigmoidf_(gz + acc[2 + ct][r]);
                const float ng = tanhf_(gn + rg * (acc[4 + ct][r] + bhhn[ct]));
                float h = st[ct * 4 + r];
                h = ng + zg * (h - ng);
                st[ct * 4 + r] = h;
                hxn[row * 264 + ob] = (__bf16)h;
            }
        }
        __syncthreads();
        cur = nxt;
    }

    float* finp = isX ? (hxfin + (long)wg * 16 * 256) : hmfin;
#pragma unroll
    for (int ct = 0; ct < 2; ct++) {
        const int ob = v * 32 + ct * 16 + l15;
#pragma unroll
        for (int r = 0; r < 4; r++)
            finp[(quad * 4 + r) * 256 + ob] = st[ct * 4 + r];
    }
}

// ---------------- K5: cosine gate at t=T-1 -> output ----------------
__global__ void finalize(const float* __restrict__ hxfin, const float* __restrict__ hmfin,
                         const float* __restrict__ W_sx, const float* __restrict__ b_sx,
                         const float* __restrict__ W_sm, const float* __restrict__ b_sm,
                         float* __restrict__ out)
{
    const int b = blockIdx.x;      // 256
    const int lane = threadIdx.x;  // 64
    float qx[4], qm[4];
#pragma unroll
    for (int s = 0; s < 4; s++) {
        float px = 0.f, pm = 0.f;
#pragma unroll
        for (int i = 0; i < 4; i++) {
            int h = i * 64 + lane;
            px += W_sx[s * 256 + h] * hxfin[b * 256 + h];
            pm += W_sm[s * 256 + h] * hmfin[h];
        }
        for (int off = 32; off; off >>= 1) { px += __shfl_xor(px, off); pm += __shfl_xor(pm, off); }
        qx[s] = px + b_sx[s];
        qm[s] = pm + b_sm[s];
    }
    float num = 0.f, nx = 0.f, nm = 0.f;
#pragma unroll
    for (int s = 0; s < 4; s++) { num += qx[s] * qm[s]; nx += qx[s] * qx[s]; nm += qm[s] * qm[s]; }
    const float den = fmaxf(sqrtf(nx), 1e-8f) * fmaxf(sqrtf(nm), 1e-8f);
    const float g = 1.0f / (1.0f + __expf(-num / den));
#pragma unroll
    for (int i = 0; i < 4; i++) {
        int h = i * 64 + lane;
        out[b * 256 + h] = g * hxfin[b * 256 + h] + (1.0f - g) * hmfin[h];
    }
}

extern "C" void kernel_launch(void* const* d_in, const int* in_sizes, int n_in,
                              void* d_out, int out_size, void* d_ws, size_t ws_size,
                              hipStream_t stream)
{
    (void)in_sizes; (void)n_in; (void)out_size; (void)ws_size;
    const float* x      = (const float*)d_in[0];
    const float* W_emb  = (const float*)d_in[1];
    const float* b_emb  = (const float*)d_in[2];
    const float* gamma  = (const float*)d_in[3];
    const float* beta   = (const float*)d_in[4];
    const float* memory = (const float*)d_in[5];
    const float* w_ih_x = (const float*)d_in[6];
    const float* w_hh_x = (const float*)d_in[7];
    const float* b_ih_x = (const float*)d_in[8];
    const float* b_hh_x = (const float*)d_in[9];
    const float* w_ih_m = (const float*)d_in[10];
    const float* w_hh_m = (const float*)d_in[11];
    const float* b_ih_m = (const float*)d_in[12];
    const float* b_hh_m = (const float*)d_in[13];
    const float* W_sx   = (const float*)d_in[14];
    const float* b_sx   = (const float*)d_in[15];
    const float* W_sm   = (const float*)d_in[16];
    const float* b_sm   = (const float*)d_in[17];
    float* out = (float*)d_out;
    char* ws = (char*)d_ws;

    __bf16* xb    = (__bf16*)(ws + OFF_XB);
    __bf16* wembb = (__bf16*)(ws + OFF_WEMB);
    __bf16* whxb  = (__bf16*)(ws + OFF_WHX);
    __bf16* whmb  = (__bf16*)(ws + OFF_WHM);
    float*  sums  = (float*)(ws + OFF_SUM);
    float*  ssqs  = (float*)(ws + OFF_SSQ);
    float*  biasx = (float*)(ws + OFF_BIASX);
    __bf16* gim   = (__bf16*)(ws + OFF_GIM);
    __bf16* eact  = (__bf16*)(ws + OFF_EACT);
    __bf16* gi    = (__bf16*)(ws + OFF_GI);
    float*  hxf   = (float*)(ws + OFF_HXF);
    float*  hmf   = (float*)(ws + OFF_HMF);
    __bf16* wpx   = (__bf16*)(ws + OFF_WPX);

    prep<<<18432, 256, 0, stream>>>(x, W_emb, w_hh_x, w_hh_m, xb, wembb, whxb, whmb, sums);
    gemm_e<<<dim3(256, 8), 256, 0, stream>>>(xb, wembb, b_emb, eact, sums, ssqs, 128, 1024);
    build_misc<<<3840, 64, 0, stream>>>(w_ih_x, b_ih_x, b_hh_x, sums, ssqs, gamma, beta, wpx, biasx,
                                        memory, w_ih_m, b_ih_m, b_hh_m, gim);
    gemm_gi3<<<dim3(128, 2), 1024, 0, stream>>>(eact, wpx, biasx, gi);
    recurrence<<<17, 512, 0, stream>>>(gi, gim, whxb, whmb, b_hh_x, b_hh_m, hxf, hmf);
    finalize<<<256, 64, 0, stream>>>(hxf, hmf, W_sx, b_sx, W_sm, b_sm, out);
}